// Round 9
// baseline (240.533 us; speedup 1.0000x reference)
//
#include <hip/hip_runtime.h>

typedef unsigned int uint32;
using half2v  = __attribute__((ext_vector_type(2))) _Float16;
using half4v  = __attribute__((ext_vector_type(4))) _Float16;
using half8   = __attribute__((ext_vector_type(8))) _Float16;
using floatx4 = __attribute__((ext_vector_type(4))) float;

__device__ __forceinline__ float sigm_f(float x){
  return __builtin_amdgcn_rcpf(1.0f + __expf(-x));
}
__device__ __forceinline__ float silu_f(float x){ return x * sigm_f(x); }

__device__ __forceinline__ half2v pkrtz(float a, float b){
  return __builtin_bit_cast(half2v, __builtin_amdgcn_cvt_pkrtz(a, b));
}

// ---------------------------------------------------------------------------
// fp16 weight blob layout (element offsets): see previous rounds.
// ---------------------------------------------------------------------------
#define OFF_W2    196608
#define OFF_HEAD  307200
#define OFF_WDT   330240
#define OFF_ROBJ  340608
#define OFF_DWB   345216
#define WTOT      346368

// padded expand buffer, CHANNEL-GROUP-MAJOR: per branch [g=24][pp=143552][8ch]
#define PPOS 143552L
#define EXPAD_ELEMS 27561984L   // 24*143552*8
// stem output, CHANNEL-GROUP-MAJOR: [g=12][n=134400][8ch]
#define NDW  134400L

__global__ __launch_bounds__(256) void wconv_k(
    const float* __restrict__ s0, const float* __restrict__ s1,
    const float* __restrict__ s2, const float* __restrict__ cw1,
    const float* __restrict__ rw1, const float* __restrict__ cw2,
    const float* __restrict__ rw2, const float* __restrict__ chw,
    const float* __restrict__ cwd, const float* __restrict__ rwd,
    const float* __restrict__ rpw, const float* __restrict__ opw,
    const float* __restrict__ cbd, const float* __restrict__ rbd,
    _Float16* __restrict__ dst)
{
  int i = blockIdx.x*256 + threadIdx.x;
  if (i >= WTOT) return;
  float v;
  if (i < OFF_WDT) {
    const float* p; int off;
    if      (i < 12288)  { p = s0;  off = i; }
    else if (i < 36864)  { p = s1;  off = i - 12288; }
    else if (i < 86016)  { p = s2;  off = i - 36864; }
    else if (i < 141312) { p = cw1; off = i - 86016; }
    else if (i < 196608) { p = rw1; off = i - 141312; }
    else if (i < 251904) { p = cw2; off = i - 196608; }
    else if (i < 307200) { p = rw2; off = i - 251904; }
    else                 { p = chw; off = i - 307200; }
    v = p[off];
  } else if (i < OFF_ROBJ) {
    int rel = i - OFF_WDT;
    int br = rel / 5184; int r2 = rel - br*5184;
    int lvl = r2 / 1728; int r3 = r2 - lvl*1728;
    int j = r3 / 192;    int c = r3 - j*192;
    const float* wd = br ? rwd : cwd;
    v = wd[lvl*1728 + c*9 + j];
  } else if (i < OFF_DWB) {
    int rel = i - OFF_ROBJ;
    int lvl = rel / 1536; int r2 = rel - lvl*1536;
    int co = r2 / 96;     int k = r2 - co*96;
    v = (co < 4) ? rpw[lvl*384 + co*96 + k] : (co == 4 ? opw[lvl*96 + k] : 0.f);
  } else {
    int rel = i - OFF_DWB;
    int br = rel / 576;  int r2 = rel - br*576;
    int lvl = r2 / 192;  int c = r2 - lvl*192;
    v = (br ? rbd : cbd)[lvl*192 + c];
  }
  dst[i] = (_Float16)v;
}

// ---------------------------------------------------------------------------
// Zero the 1-pixel border of the padded expand buffers (channel-major).
// ---------------------------------------------------------------------------
__global__ __launch_bounds__(256) void zpad_k(_Float16* __restrict__ exBase)
{
  int ci = blockIdx.x*256 + threadIdx.x;
  if (ci >= 439296) return;
  int br = ci / 219648; int r = ci - br*219648;
  int W, PLB, rem, perimg;
  if (r < 124416)      { W=80; PLB=0;      rem = r;          perimg = 7776; }
  else if (r < 187392) { W=40; PLB=107584; rem = r - 124416; perimg = 3936; }
  else                 { W=20; PLB=135808; rem = r - 187392; perimg = 2016; }
  int b = rem / perimg; int t3 = rem - b*perimg;
  int p = t3 / 24; int g = t3 - p*24;
  int PW = W + 2;
  int row, col;
  if (p < 2*PW) { row = (p >= PW) ? (W+1) : 0; col = (p >= PW) ? (p - PW) : p; }
  else { int q = p - 2*PW; row = 1 + (q >> 1); col = (q & 1) ? (W+1) : 0; }
  long pp = (long)PLB + (long)b*PW*PW + row*PW + col;
  half8 z = {(_Float16)0,(_Float16)0,(_Float16)0,(_Float16)0,
             (_Float16)0,(_Float16)0,(_Float16)0,(_Float16)0};
  *(half8*)(exBase + br*EXPAD_ELEMS + ((long)g*PPOS + pp)*8) = z;
}

// ---------------------------------------------------------------------------
// Stem GEMM from NCHW fp32, fp16 MFMA. Output CHANNEL-GROUP-MAJOR [g][n][8].
// ---------------------------------------------------------------------------
__global__ __launch_bounds__(256) void stem_k(
    const float* __restrict__ x0, const float* __restrict__ x1,
    const float* __restrict__ x2, const _Float16* __restrict__ Wb,
    const float* __restrict__ sb0, const float* __restrict__ sb1,
    const float* __restrict__ sb2, _Float16* __restrict__ Out)
{
  const int m0 = blockIdx.x << 7;
  const int lvl = (m0 < 102400) ? 0 : (m0 < 128000 ? 1 : 2);
  const int CIN = (lvl==0)?128:(lvl==1?256:512);
  const int HW  = (lvl==0)?6400:(lvl==1?1600:400);
  const int noff= (lvl==0)?0:(lvl==1?102400:128000);
  const float* X = (lvl==0)?x0:(lvl==1?x1:x2);
  const _Float16* Wl = Wb + ((lvl==0)?0:(lvl==1?12288:36864));
  const float* bias = (lvl==0)?sb0:(lvl==1?sb1:sb2);

  int t=threadIdx.x, lane=t&63, wv=t>>6, mr=lane&15, quad=lane>>4;

  int idx[2];
  #pragma unroll
  for (int nt=0; nt<2; ++nt) {
    int n = m0 + wv*32 + nt*16 + mr;
    int m = n - noff; int b_ = m / HW; int p = m - b_*HW;
    idx[nt] = (b_*CIN + quad*8)*HW + p;
  }
  const _Float16* Ap = Wl + mr*CIN + quad*8;

  floatx4 zero = {0.f,0.f,0.f,0.f};
  floatx4 acc[6][2];
  #pragma unroll
  for (int i=0;i<6;++i)
    #pragma unroll
    for (int j=0;j<2;++j) acc[i][j] = zero;

  for (int k=0; k<CIN; k+=32) {
    half8 a[6], b[2];
    #pragma unroll
    for (int mt=0; mt<6; ++mt) a[mt] = *(const half8*)(Ap + mt*16*CIN);
    #pragma unroll
    for (int nt=0; nt<2; ++nt) {
      float f[8];
      #pragma unroll
      for (int j=0;j<8;++j) f[j] = X[idx[nt] + j*HW];
      half2v* bh = (half2v*)&b[nt];
      #pragma unroll
      for (int j=0;j<4;++j) bh[j] = pkrtz(f[2*j], f[2*j+1]);
    }
    #pragma unroll
    for (int mt=0; mt<6; ++mt)
      #pragma unroll
      for (int nt=0; nt<2; ++nt)
        acc[mt][nt] = __builtin_amdgcn_mfma_f32_16x16x32_f16(a[mt], b[nt], acc[mt][nt], 0, 0, 0);
    Ap += 32;
    #pragma unroll
    for (int nt=0; nt<2; ++nt) idx[nt] += 32*HW;
  }

  #pragma unroll
  for (int mt=0; mt<6; ++mt) {
    float4 bv = *(const float4*)(bias + mt*16 + quad*4);
    int co = mt*16 + quad*4;
    int g = co >> 3; int h = co & 7;
    #pragma unroll
    for (int nt=0; nt<2; ++nt) {
      int pos = m0 + wv*32 + nt*16 + mr;
      half4v o;
      o[0] = (_Float16)silu_f(acc[mt][nt][0] + bv.x);
      o[1] = (_Float16)silu_f(acc[mt][nt][1] + bv.y);
      o[2] = (_Float16)silu_f(acc[mt][nt][2] + bv.z);
      o[3] = (_Float16)silu_f(acc[mt][nt][3] + bv.w);
      *(half4v*)(Out + ((long)g*NDW + pos)*8 + h) = o;
    }
  }
}

// ---------------------------------------------------------------------------
// Expand GEMM, both branches: channel-major stemO -> channel-major padded.
// grid (1050, 2, 2).
// ---------------------------------------------------------------------------
__global__ __launch_bounds__(256) void expand2_k(
    const _Float16* __restrict__ A, const _Float16* __restrict__ wbf,
    const float* __restrict__ b1c, const float* __restrict__ b1r,
    _Float16* __restrict__ OutBase)
{
  const int bz = blockIdx.z;
  const _Float16* Wb = wbf + 86016 + bz*55296;
  _Float16* Out = OutBase + bz*EXPAD_ELEMS;
  const float* b1 = bz ? b1r : b1c;

  const int m0 = blockIdx.x << 7;
  const int lvl = (m0 < 102400) ? 0 : (m0 < 128000 ? 1 : 2);
  const int HW  = (lvl==0)?6400:(lvl==1?1600:400);
  const int W   = (lvl==0)?80:(lvl==1?40:20);
  const int noff= (lvl==0)?0:(lvl==1?102400:128000);
  const int PLB = (lvl==0)?0:(lvl==1?107584:135808);
  const int PW  = W + 2;
  const int co0 = blockIdx.y * 96;
  int t = threadIdx.x, lane = t & 63, wv = t >> 6;
  int mr = lane & 15, quad = lane >> 4;
  const _Float16* Ap0 = A + ((long)quad*NDW + (m0 + wv*32 + mr))*8;  // acts, ch-major
  const _Float16* Bp = Wb + ((long)(co0 + mr))*96 + quad*8;          // weights
  const float* bp = b1 + lvl*192 + co0;

  floatx4 zero = {0.f,0.f,0.f,0.f};
  floatx4 acc[6][2];     // [co tile][pos tile]
  #pragma unroll
  for (int i=0;i<6;++i)
    #pragma unroll
    for (int j=0;j<2;++j) acc[i][j] = zero;

  #pragma unroll
  for (int k=0; k<3; ++k) {
    half8 wf[6], af[2];
    #pragma unroll
    for (int mt=0; mt<6; ++mt) wf[mt] = *(const half8*)(Bp + (long)mt*16*96);
    #pragma unroll
    for (int nt=0; nt<2; ++nt)
      af[nt] = *(const half8*)(Ap0 + ((long)k*4*NDW)*8 + nt*16*8);
    #pragma unroll
    for (int mt=0; mt<6; ++mt)
      #pragma unroll
      for (int nt=0; nt<2; ++nt)
        acc[mt][nt] = __builtin_amdgcn_mfma_f32_16x16x32_f16(wf[mt], af[nt], acc[mt][nt], 0, 0, 0);
    Bp += 32;
  }

  long pp2[2];
  #pragma unroll
  for (int nt=0; nt<2; ++nt) {
    int gm = m0 + wv*32 + nt*16 + mr;
    int m = gm - noff; int b_ = m / HW; int rp = m - b_*HW;
    int y = rp / W;  int x = rp - y*W;
    pp2[nt] = PLB + ((long)b_*PW + (y+1))*PW + (x+1);
  }

  #pragma unroll
  for (int mt=0; mt<6; ++mt) {
    float4 bv = *(const float4*)(bp + mt*16 + quad*4);
    int co = co0 + mt*16 + quad*4;
    int g = co >> 3;            // channel group
    int h = (co & 4);           // 0 or 4 within group
    #pragma unroll
    for (int nt=0; nt<2; ++nt) {
      half4v o;
      o[0] = (_Float16)silu_f(acc[mt][nt][0] + bv.x);
      o[1] = (_Float16)silu_f(acc[mt][nt][1] + bv.y);
      o[2] = (_Float16)silu_f(acc[mt][nt][2] + bv.z);
      o[3] = (_Float16)silu_f(acc[mt][nt][3] + bv.w);
      *(half4v*)(Out + ((long)g*PPOS + pp2[nt])*8 + h) = o;
    }
  }
}

// ---------------------------------------------------------------------------
// FUSED dw3x3 + proj + heads, ZERO BARRIERS.
// Key: thread (wv,mr,quad) computes the dw conv for position wv*16+mr,
// channel group g=4k+quad at k-step k -- exactly the proj MFMA B-fragment.
// dw output never leaves registers; no dw LDS, no syncthreads at all.
// LDS only 64x104 fp16 (13.3KB) for intra-wave proj->head handoff.
// grid (2100, 2): x = 64-pos tile, y = branch.
// ---------------------------------------------------------------------------
#define PSTRIDE 104
__global__ __launch_bounds__(256, 4) void dwprojhead_k(
    const _Float16* __restrict__ exBase, const _Float16* __restrict__ wbf,
    const float* __restrict__ b2_c, const float* __restrict__ b2_r,
    const _Float16* __restrict__ resid,
    const float* __restrict__ hb, const float* __restrict__ rb,
    const float* __restrict__ ob, float* __restrict__ out)
{
  __shared__ _Float16 ldsP[64*PSTRIDE];   // proj out [pos][96], intra-wave only
  const int bz = blockIdx.y;
  const _Float16* ex = exBase + bz*EXPAD_ELEMS;
  const float* b2 = bz ? b2_r : b2_c;

  const int m0 = blockIdx.x << 6;
  const int lvl = (m0 < 102400) ? 0 : (m0 < 128000 ? 1 : 2);
  const int HW  = (lvl==0) ? 6400 : (lvl==1 ? 1600 : 400);
  const int W   = (lvl==0) ? 80 : (lvl==1 ? 40 : 20);
  const int noff= (lvl==0) ? 0 : (lvl==1 ? 102400 : 128000);
  const int a0  = (lvl==0) ? 0 : (lvl==1 ? 6400 : 8000);
  const int PLB = (lvl==0) ? 0 : (lvl==1 ? 107584 : 135808);
  const int PW  = W + 2;

  int t = threadIdx.x, lane = t & 63, wv = t >> 6;
  int mr = lane & 15, quad = lane >> 4;

  // this thread's position (N col of the proj MFMA)
  int n = m0 + wv*16 + mr;
  int m = n - noff; int b_ = m / HW; int rp = m - b_*HW;
  int y = rp / W;  int x = rp - y*W;
  long pp = (long)PLB + ((long)b_*PW + (y+1))*PW + (x+1);

  const _Float16* wT = wbf + OFF_WDT + bz*5184 + lvl*1728;
  const _Float16* bB = wbf + OFF_DWB + bz*576 + lvl*192;
  const _Float16* Ap = wbf + OFF_W2 + bz*55296 + lvl*18432 + ((long)mr)*192 + quad*8;

  floatx4 pacc[6];
  {
    floatx4 zero = {0.f,0.f,0.f,0.f};
    #pragma unroll
    for (int j=0;j<6;++j) pacc[j] = zero;
  }

  // ---- fused dw + proj k-loop: dw fragment computed in-register ----
  for (int k = 0; k < 6; ++k) {
    const int g = 4*k + quad;                  // this lane's K-slice group
    const _Float16* exg = ex + ((long)g*PPOS + pp)*8;
    const _Float16* wp = wT + g*8;

    half8 a[9], w[9];
    #pragma unroll
    for (int dy = 0; dy < 3; ++dy)
      #pragma unroll
      for (int dx = 0; dx < 3; ++dx)
        a[dy*3+dx] = *(const half8*)(exg + ((long)(dy-1)*PW + (dx-1))*8);
    #pragma unroll
    for (int tap = 0; tap < 9; ++tap)
      w[tap] = *(const half8*)(wp + tap*192);
    half8 bv8 = *(const half8*)(bB + g*8);
    half8 wf[6];
    #pragma unroll
    for (int mt = 0; mt < 6; ++mt)
      wf[mt] = *(const half8*)(Ap + (long)mt*16*192 + k*32);

    half2v ac0 = {bv8[0], bv8[1]};
    half2v ac1 = {bv8[2], bv8[3]};
    half2v ac2 = {bv8[4], bv8[5]};
    half2v ac3 = {bv8[6], bv8[7]};
    #pragma unroll
    for (int tap = 0; tap < 9; ++tap) {
      ac0 += half2v{a[tap][0],a[tap][1]} * half2v{w[tap][0],w[tap][1]};
      ac1 += half2v{a[tap][2],a[tap][3]} * half2v{w[tap][2],w[tap][3]};
      ac2 += half2v{a[tap][4],a[tap][5]} * half2v{w[tap][4],w[tap][5]};
      ac3 += half2v{a[tap][6],a[tap][7]} * half2v{w[tap][6],w[tap][7]};
    }
    half8 af;
    {
      half2v* oh = (half2v*)&af;
      oh[0] = pkrtz(silu_f((float)ac0[0]), silu_f((float)ac0[1]));
      oh[1] = pkrtz(silu_f((float)ac1[0]), silu_f((float)ac1[1]));
      oh[2] = pkrtz(silu_f((float)ac2[0]), silu_f((float)ac2[1]));
      oh[3] = pkrtz(silu_f((float)ac3[0]), silu_f((float)ac3[1]));
    }
    #pragma unroll
    for (int mt = 0; mt < 6; ++mt)
      pacc[mt] = __builtin_amdgcn_mfma_f32_16x16x32_f16(wf[mt], af, pacc[mt], 0, 0, 0);
  }

  // ---- epilogue: + bias + residual (channel-major) -> ldsP [pos][co] ----
  {
    const float* bp2 = b2 + lvl*96;
    int row = wv*16 + mr;            // pos within block (this lane's N col)
    #pragma unroll
    for (int mt=0; mt<6; ++mt) {
      int co = mt*16 + quad*4;
      float4 bv = *(const float4*)(bp2 + co);
      int g = co >> 3; int h = co & 7;
      half4v rs = *(const half4v*)(resid + ((long)g*NDW + n)*8 + h);
      half4v o;
      o[0] = (_Float16)(pacc[mt][0] + bv.x + (float)rs[0]);
      o[1] = (_Float16)(pacc[mt][1] + bv.y + (float)rs[1]);
      o[2] = (_Float16)(pacc[mt][2] + bv.z + (float)rs[2]);
      o[3] = (_Float16)(pacc[mt][3] + bv.w + (float)rs[3]);
      *(half4v*)(ldsP + row*PSTRIDE + co) = o;
    }
  }
  // heads read only this wave's 16 rows -> no barrier (same-wave ds ordering).

  // ---- heads ----
  if (bz == 0) {
    const _Float16* Bp = wbf + OFF_HEAD + lvl*7680 + ((long)mr)*96 + quad*8;
    const float* bp = hb + lvl*80;
    floatx4 zero = {0.f,0.f,0.f,0.f};
    floatx4 acc[5];
    #pragma unroll
    for (int j=0;j<5;++j) acc[j] = zero;

    #pragma unroll
    for (int k=0; k<3; ++k) {
      half8 a = *(const half8*)(ldsP + (wv*16 + mr)*PSTRIDE + k*32 + quad*8);
      half8 b[5];
      #pragma unroll
      for (int nt=0; nt<5; ++nt)
        b[nt] = *(const half8*)(Bp + (long)nt*16*96 + k*32);
      #pragma unroll
      for (int nt=0; nt<5; ++nt)
        acc[nt] = __builtin_amdgcn_mfma_f32_16x16x32_f16(a, b[nt], acc[nt], 0, 0, 0);
    }

    #pragma unroll
    for (int nt=0; nt<5; ++nt) {
      int co = nt*16 + mr;
      float bv = bp[co];
      int pos = m0 + wv*16 + quad*4;
      #pragma unroll
      for (int r=0; r<4; ++r) {
        int mm = pos + r - noff; int bb = mm / HW; int rpp = mm - bb*HW;
        out[((long)(bb*8400 + a0 + rpp))*85 + 5 + co] = sigm_f(acc[nt][r] + bv);
      }
    }
  } else {
    const _Float16* Bp = wbf + OFF_ROBJ + lvl*1536 + ((long)mr)*96 + quad*8;
    float bv = (mr < 4) ? rb[lvl*4 + mr] : ((mr == 4) ? ob[lvl] : 0.f);
    float sc = (lvl==0) ? 8.f : (lvl==1 ? 16.f : 32.f);
    floatx4 acc = {0.f,0.f,0.f,0.f};
    #pragma unroll
    for (int k=0; k<3; ++k) {
      half8 a = *(const half8*)(ldsP + (wv*16 + mr)*PSTRIDE + k*32 + quad*8);
      half8 b = *(const half8*)(Bp + k*32);
      acc = __builtin_amdgcn_mfma_f32_16x16x32_f16(a, b, acc, 0, 0, 0);
    }
    #pragma unroll
    for (int r=0; r<4; ++r) {
      int pos = m0 + wv*16 + quad*4 + r;
      int mm = pos - noff; int bb = mm / HW; int rpp = mm - bb*HW;
      int yy = rpp / W;  int xx = rpp - yy*W;
      float v = acc[r] + bv;
      float o;
      if      (mr == 0) o = (v + (float)xx)*sc;
      else if (mr == 1) o = (v + (float)yy)*sc;
      else if (mr <  4) o = __expf(v)*sc;
      else              o = sigm_f(v);
      if (mr < 5)
        out[((long)(bb*8400 + a0 + rpp))*85 + mr] = o;
    }
  }
}

extern "C" void kernel_launch(void* const* d_in, const int* in_sizes, int n_in,
                              void* d_out, int out_size, void* d_ws, size_t ws_size,
                              hipStream_t stream)
{
  bool dict = (in_sizes[1] == 96*128);
  const float* X[3]; const float* SW[3]; const float* SB[3];
  if (dict) {
    X[0]=(const float*)d_in[0]; SW[0]=(const float*)d_in[1]; SB[0]=(const float*)d_in[2];
    X[1]=(const float*)d_in[3]; SW[1]=(const float*)d_in[4]; SB[1]=(const float*)d_in[5];
    X[2]=(const float*)d_in[6]; SW[2]=(const float*)d_in[7]; SB[2]=(const float*)d_in[8];
  } else {
    X[0]=(const float*)d_in[0]; X[1]=(const float*)d_in[1]; X[2]=(const float*)d_in[2];
    SW[0]=(const float*)d_in[3]; SB[0]=(const float*)d_in[4];
    SW[1]=(const float*)d_in[5]; SB[1]=(const float*)d_in[6];
    SW[2]=(const float*)d_in[7]; SB[2]=(const float*)d_in[8];
  }
  const float* br_w1[2] = {(const float*)d_in[9],  (const float*)d_in[15]};
  const float* br_b1[2] = {(const float*)d_in[10], (const float*)d_in[16]};
  const float* br_wd[2] = {(const float*)d_in[11], (const float*)d_in[17]};
  const float* br_bd[2] = {(const float*)d_in[12], (const float*)d_in[18]};
  const float* br_w2[2] = {(const float*)d_in[13], (const float*)d_in[19]};
  const float* br_b2[2] = {(const float*)d_in[14], (const float*)d_in[20]};
  const float* clsp_w=(const float*)d_in[21]; const float* clsp_b=(const float*)d_in[22];
  const float* regp_w=(const float*)d_in[23]; const float* regp_b=(const float*)d_in[24];
  const float* objp_w=(const float*)d_in[25]; const float* objp_b=(const float*)d_in[26];

  float* out = (float*)d_out;

  // workspace (fp16 units): wbf 346368 + stemO 12,902,400 + bufA 2x27,561,984
  _Float16* wbf   = (_Float16*)d_ws;
  _Float16* stemO = wbf + WTOT;
  _Float16* bufA  = stemO + 12902400;

  // 1. weights/bias -> fp16 blob
  wconv_k<<<1353,256,0,stream>>>(SW[0],SW[1],SW[2],br_w1[0],br_w1[1],
                                 br_w2[0],br_w2[1],clsp_w,br_wd[0],br_wd[1],
                                 regp_w,objp_w,br_bd[0],br_bd[1],wbf);

  // 2. zero the padded borders of the expand buffers
  zpad_k<<<1716,256,0,stream>>>(bufA);

  // 3. stem GEMM straight from NCHW fp32, channel-major output
  stem_k<<<1050,256,0,stream>>>(X[0],X[1],X[2],wbf,SB[0],SB[1],SB[2],stemO);

  // 4. expand GEMM, both branches, channel-major padded output
  expand2_k<<<dim3(1050,2,2),256,0,stream>>>(stemO, wbf, br_b1[0], br_b1[1], bufA);

  // 5. FUSED dw3x3 + project + residual + heads (zero barriers)
  dwprojhead_k<<<dim3(2100,2),256,0,stream>>>(
      bufA, wbf, br_b2[0], br_b2[1], stemO,
      clsp_b, regp_b, objp_b, out);
}

// Round 10
// 240.001 us; speedup vs baseline: 1.0022x; 1.0022x over previous
//
#include <hip/hip_runtime.h>

typedef unsigned int uint32;
using half2v  = __attribute__((ext_vector_type(2))) _Float16;
using half4v  = __attribute__((ext_vector_type(4))) _Float16;
using half8   = __attribute__((ext_vector_type(8))) _Float16;
using floatx4 = __attribute__((ext_vector_type(4))) float;

__device__ __forceinline__ float sigm_f(float x){
  return __builtin_amdgcn_rcpf(1.0f + __expf(-x));
}
__device__ __forceinline__ float silu_f(float x){ return x * sigm_f(x); }

__device__ __forceinline__ half2v pkrtz(float a, float b){
  return __builtin_bit_cast(half2v, __builtin_amdgcn_cvt_pkrtz(a, b));
}

// ---------------------------------------------------------------------------
// fp16 weight blob layout (element offsets): see previous rounds.
// ---------------------------------------------------------------------------
#define OFF_W2    196608
#define OFF_HEAD  307200
#define OFF_WDT   330240
#define OFF_ROBJ  340608
#define OFF_DWB   345216
#define WTOT      346368

// padded expand buffer, CHANNEL-GROUP-MAJOR: per branch [g=24][pp=143552][8ch]
#define PPOS 143552L
#define EXPAD_ELEMS 27561984L   // 24*143552*8
// stem output, CHANNEL-GROUP-MAJOR: [g=12][n=134400][8ch]
#define NDW  134400L

__global__ __launch_bounds__(256) void wconv_k(
    const float* __restrict__ s0, const float* __restrict__ s1,
    const float* __restrict__ s2, const float* __restrict__ cw1,
    const float* __restrict__ rw1, const float* __restrict__ cw2,
    const float* __restrict__ rw2, const float* __restrict__ chw,
    const float* __restrict__ cwd, const float* __restrict__ rwd,
    const float* __restrict__ rpw, const float* __restrict__ opw,
    const float* __restrict__ cbd, const float* __restrict__ rbd,
    _Float16* __restrict__ dst)
{
  int i = blockIdx.x*256 + threadIdx.x;
  if (i >= WTOT) return;
  float v;
  if (i < OFF_WDT) {
    const float* p; int off;
    if      (i < 12288)  { p = s0;  off = i; }
    else if (i < 36864)  { p = s1;  off = i - 12288; }
    else if (i < 86016)  { p = s2;  off = i - 36864; }
    else if (i < 141312) { p = cw1; off = i - 86016; }
    else if (i < 196608) { p = rw1; off = i - 141312; }
    else if (i < 251904) { p = cw2; off = i - 196608; }
    else if (i < 307200) { p = rw2; off = i - 251904; }
    else                 { p = chw; off = i - 307200; }
    v = p[off];
  } else if (i < OFF_ROBJ) {
    int rel = i - OFF_WDT;
    int br = rel / 5184; int r2 = rel - br*5184;
    int lvl = r2 / 1728; int r3 = r2 - lvl*1728;
    int j = r3 / 192;    int c = r3 - j*192;
    const float* wd = br ? rwd : cwd;
    v = wd[lvl*1728 + c*9 + j];
  } else if (i < OFF_DWB) {
    int rel = i - OFF_ROBJ;
    int lvl = rel / 1536; int r2 = rel - lvl*1536;
    int co = r2 / 96;     int k = r2 - co*96;
    v = (co < 4) ? rpw[lvl*384 + co*96 + k] : (co == 4 ? opw[lvl*96 + k] : 0.f);
  } else {
    int rel = i - OFF_DWB;
    int br = rel / 576;  int r2 = rel - br*576;
    int lvl = r2 / 192;  int c = r2 - lvl*192;
    v = (br ? rbd : cbd)[lvl*192 + c];
  }
  dst[i] = (_Float16)v;
}

// ---------------------------------------------------------------------------
// Zero the 1-pixel border of the padded expand buffers (channel-major).
// ---------------------------------------------------------------------------
__global__ __launch_bounds__(256) void zpad_k(_Float16* __restrict__ exBase)
{
  int ci = blockIdx.x*256 + threadIdx.x;
  if (ci >= 439296) return;
  int br = ci / 219648; int r = ci - br*219648;
  int W, PLB, rem, perimg;
  if (r < 124416)      { W=80; PLB=0;      rem = r;          perimg = 7776; }
  else if (r < 187392) { W=40; PLB=107584; rem = r - 124416; perimg = 3936; }
  else                 { W=20; PLB=135808; rem = r - 187392; perimg = 2016; }
  int b = rem / perimg; int t3 = rem - b*perimg;
  int p = t3 / 24; int g = t3 - p*24;
  int PW = W + 2;
  int row, col;
  if (p < 2*PW) { row = (p >= PW) ? (W+1) : 0; col = (p >= PW) ? (p - PW) : p; }
  else { int q = p - 2*PW; row = 1 + (q >> 1); col = (q & 1) ? (W+1) : 0; }
  long pp = (long)PLB + (long)b*PW*PW + row*PW + col;
  half8 z = {(_Float16)0,(_Float16)0,(_Float16)0,(_Float16)0,
             (_Float16)0,(_Float16)0,(_Float16)0,(_Float16)0};
  *(half8*)(exBase + br*EXPAD_ELEMS + ((long)g*PPOS + pp)*8) = z;
}

// ---------------------------------------------------------------------------
// Stem GEMM from NCHW fp32, fp16 MFMA. Output CHANNEL-GROUP-MAJOR [g][n][8].
// ---------------------------------------------------------------------------
__global__ __launch_bounds__(256) void stem_k(
    const float* __restrict__ x0, const float* __restrict__ x1,
    const float* __restrict__ x2, const _Float16* __restrict__ Wb,
    const float* __restrict__ sb0, const float* __restrict__ sb1,
    const float* __restrict__ sb2, _Float16* __restrict__ Out)
{
  const int m0 = blockIdx.x << 7;
  const int lvl = (m0 < 102400) ? 0 : (m0 < 128000 ? 1 : 2);
  const int CIN = (lvl==0)?128:(lvl==1?256:512);
  const int HW  = (lvl==0)?6400:(lvl==1?1600:400);
  const int noff= (lvl==0)?0:(lvl==1?102400:128000);
  const float* X = (lvl==0)?x0:(lvl==1?x1:x2);
  const _Float16* Wl = Wb + ((lvl==0)?0:(lvl==1?12288:36864));
  const float* bias = (lvl==0)?sb0:(lvl==1?sb1:sb2);

  int t=threadIdx.x, lane=t&63, wv=t>>6, mr=lane&15, quad=lane>>4;

  int idx[2];
  #pragma unroll
  for (int nt=0; nt<2; ++nt) {
    int n = m0 + wv*32 + nt*16 + mr;
    int m = n - noff; int b_ = m / HW; int p = m - b_*HW;
    idx[nt] = (b_*CIN + quad*8)*HW + p;
  }
  const _Float16* Ap = Wl + mr*CIN + quad*8;

  floatx4 zero = {0.f,0.f,0.f,0.f};
  floatx4 acc[6][2];
  #pragma unroll
  for (int i=0;i<6;++i)
    #pragma unroll
    for (int j=0;j<2;++j) acc[i][j] = zero;

  for (int k=0; k<CIN; k+=32) {
    half8 a[6], b[2];
    #pragma unroll
    for (int mt=0; mt<6; ++mt) a[mt] = *(const half8*)(Ap + mt*16*CIN);
    #pragma unroll
    for (int nt=0; nt<2; ++nt) {
      float f[8];
      #pragma unroll
      for (int j=0;j<8;++j) f[j] = X[idx[nt] + j*HW];
      half2v* bh = (half2v*)&b[nt];
      #pragma unroll
      for (int j=0;j<4;++j) bh[j] = pkrtz(f[2*j], f[2*j+1]);
    }
    #pragma unroll
    for (int mt=0; mt<6; ++mt)
      #pragma unroll
      for (int nt=0; nt<2; ++nt)
        acc[mt][nt] = __builtin_amdgcn_mfma_f32_16x16x32_f16(a[mt], b[nt], acc[mt][nt], 0, 0, 0);
    Ap += 32;
    #pragma unroll
    for (int nt=0; nt<2; ++nt) idx[nt] += 32*HW;
  }

  #pragma unroll
  for (int mt=0; mt<6; ++mt) {
    float4 bv = *(const float4*)(bias + mt*16 + quad*4);
    int co = mt*16 + quad*4;
    int g = co >> 3; int h = co & 7;
    #pragma unroll
    for (int nt=0; nt<2; ++nt) {
      int pos = m0 + wv*32 + nt*16 + mr;
      half4v o;
      o[0] = (_Float16)silu_f(acc[mt][nt][0] + bv.x);
      o[1] = (_Float16)silu_f(acc[mt][nt][1] + bv.y);
      o[2] = (_Float16)silu_f(acc[mt][nt][2] + bv.z);
      o[3] = (_Float16)silu_f(acc[mt][nt][3] + bv.w);
      *(half4v*)(Out + ((long)g*NDW + pos)*8 + h) = o;
    }
  }
}

// ---------------------------------------------------------------------------
// Expand GEMM, both branches: channel-major stemO -> channel-major padded.
// grid (1050, 2, 2). XCD-bijective swizzle on blockIdx.x (nwg=1050: q=131,r=2).
// ---------------------------------------------------------------------------
__global__ __launch_bounds__(256) void expand2_k(
    const _Float16* __restrict__ A, const _Float16* __restrict__ wbf,
    const float* __restrict__ b1c, const float* __restrict__ b1r,
    _Float16* __restrict__ OutBase)
{
  const int bz = blockIdx.z;
  const _Float16* Wb = wbf + 86016 + bz*55296;
  _Float16* Out = OutBase + bz*EXPAD_ELEMS;
  const float* b1 = bz ? b1r : b1c;

  int orig = blockIdx.x;
  int xcd = orig & 7; int loc = orig >> 3;
  int bx = (xcd < 2 ? xcd*132 : 2*132 + (xcd-2)*131) + loc;

  const int m0 = bx << 7;
  const int lvl = (m0 < 102400) ? 0 : (m0 < 128000 ? 1 : 2);
  const int HW  = (lvl==0)?6400:(lvl==1?1600:400);
  const int W   = (lvl==0)?80:(lvl==1?40:20);
  const int noff= (lvl==0)?0:(lvl==1?102400:128000);
  const int PLB = (lvl==0)?0:(lvl==1?107584:135808);
  const int PW  = W + 2;
  const int co0 = blockIdx.y * 96;
  int t = threadIdx.x, lane = t & 63, wv = t >> 6;
  int mr = lane & 15, quad = lane >> 4;
  const _Float16* Ap0 = A + ((long)quad*NDW + (m0 + wv*32 + mr))*8;  // acts, ch-major
  const _Float16* Bp = Wb + ((long)(co0 + mr))*96 + quad*8;          // weights
  const float* bp = b1 + lvl*192 + co0;

  floatx4 zero = {0.f,0.f,0.f,0.f};
  floatx4 acc[6][2];     // [co tile][pos tile]
  #pragma unroll
  for (int i=0;i<6;++i)
    #pragma unroll
    for (int j=0;j<2;++j) acc[i][j] = zero;

  #pragma unroll
  for (int k=0; k<3; ++k) {
    half8 wf[6], af[2];
    #pragma unroll
    for (int mt=0; mt<6; ++mt) wf[mt] = *(const half8*)(Bp + (long)mt*16*96);
    #pragma unroll
    for (int nt=0; nt<2; ++nt)
      af[nt] = *(const half8*)(Ap0 + ((long)k*4*NDW)*8 + nt*16*8);
    #pragma unroll
    for (int mt=0; mt<6; ++mt)
      #pragma unroll
      for (int nt=0; nt<2; ++nt)
        acc[mt][nt] = __builtin_amdgcn_mfma_f32_16x16x32_f16(wf[mt], af[nt], acc[mt][nt], 0, 0, 0);
    Bp += 32;
  }

  long pp2[2];
  #pragma unroll
  for (int nt=0; nt<2; ++nt) {
    int gm = m0 + wv*32 + nt*16 + mr;
    int m = gm - noff; int b_ = m / HW; int rp = m - b_*HW;
    int y = rp / W;  int x = rp - y*W;
    pp2[nt] = PLB + ((long)b_*PW + (y+1))*PW + (x+1);
  }

  #pragma unroll
  for (int mt=0; mt<6; ++mt) {
    float4 bv = *(const float4*)(bp + mt*16 + quad*4);
    int co = co0 + mt*16 + quad*4;
    int g = co >> 3;            // channel group
    int h = (co & 4);           // 0 or 4 within group
    #pragma unroll
    for (int nt=0; nt<2; ++nt) {
      half4v o;
      o[0] = (_Float16)silu_f(acc[mt][nt][0] + bv.x);
      o[1] = (_Float16)silu_f(acc[mt][nt][1] + bv.y);
      o[2] = (_Float16)silu_f(acc[mt][nt][2] + bv.z);
      o[3] = (_Float16)silu_f(acc[mt][nt][3] + bv.w);
      *(half4v*)(Out + ((long)g*PPOS + pp2[nt])*8 + h) = o;
    }
  }
}

// ---------------------------------------------------------------------------
// FUSED dw3x3 + proj + heads (round-8 structure) with:
//  - 2-deep software-pipelined phase 1 (explicit A0/A1 ping-pong, unrolled)
//  - __launch_bounds__(256,3): VGPR cap ~170 so taps stay in flight
//  - XCD-bijective blockIdx swizzle (nwg=2100: q=262,r=4)
//  - magic-mul division (no runtime-divisor int div)
//  - resid prefetched at kernel start
// grid (2100, 2). LDS 25088B.
// ---------------------------------------------------------------------------
#define PSTRIDE 104
__global__ __launch_bounds__(256, 3) void dwprojhead_k(
    const _Float16* __restrict__ exBase, const _Float16* __restrict__ wbf,
    const float* __restrict__ b2_c, const float* __restrict__ b2_r,
    const _Float16* __restrict__ resid,
    const float* __restrict__ hb, const float* __restrict__ rb,
    const float* __restrict__ ob, float* __restrict__ out)
{
  __shared__ _Float16 lds[64*196];   // dw out [pos][192] stride 196
  _Float16* ldsP = lds;              // reused: proj out [pos][96] stride 104
  const int bz = blockIdx.y;
  const _Float16* ex = exBase + bz*EXPAD_ELEMS;
  const float* b2 = bz ? b2_r : b2_c;

  int orig = blockIdx.x;
  int xcd = orig & 7; int loc = orig >> 3;
  int bx = (xcd < 4 ? xcd*263 : 4*263 + (xcd-4)*262) + loc;

  const int m0 = bx << 6;
  const int lvl = (m0 < 102400) ? 0 : (m0 < 128000 ? 1 : 2);
  const int HW  = (lvl==0) ? 6400 : (lvl==1 ? 1600 : 400);
  const int W   = (lvl==0) ? 80 : (lvl==1 ? 40 : 20);
  const int noff= (lvl==0) ? 0 : (lvl==1 ? 102400 : 128000);
  const int a0  = (lvl==0) ? 0 : (lvl==1 ? 6400 : 8000);
  const int PLB = (lvl==0) ? 0 : (lvl==1 ? 107584 : 135808);
  const int PW  = W + 2;
  // magic divisors: b_ = m*MB>>32 (m < 16*HW), y = rp*MW>>22 (rp < HW)
  const uint32 MB = (lvl==0) ? 671089u : (lvl==1 ? 2684355u : 10737419u);
  const uint32 MW = (lvl==0) ? 52429u  : (lvl==1 ? 104858u  : 209716u);

  int t = threadIdx.x, lane = t & 63, wv = t >> 6;
  int mr = lane & 15, quad = lane >> 4;

  // ---- resid prefetch (used in epilogue, 2 phases away) ----
  half4v rsv[6];
  {
    int n2 = m0 + wv*16 + mr;
    #pragma unroll
    for (int mt=0; mt<6; ++mt) {
      int co = mt*16 + quad*4;
      int g = co >> 3; int h = co & 7;
      rsv[mt] = *(const half4v*)(resid + ((long)g*NDW + n2)*8 + h);
    }
  }

  // ---- phase 1: dw3x3 + SiLU -> LDS, 2-deep pipelined ----
  {
    int n = m0 + lane;
    uint32 m = (uint32)(n - noff);
    uint32 b_ = (uint32)(((unsigned long long)m * MB) >> 32);
    uint32 rp = m - b_*HW;
    uint32 y = (rp * MW) >> 22;
    uint32 x = rp - y*W;
    long pp = (long)PLB + ((long)b_*PW + (y+1))*PW + (x+1);
    const _Float16* wT = wbf + OFF_WDT + bz*5184 + lvl*1728;
    const _Float16* bB = wbf + OFF_DWB + bz*576 + lvl*192;

    half8 A0[9], A1[9];

    // load taps for a group into dst
    auto LOADT = [&](half8* dst, int g) {
      const _Float16* exg = ex + ((long)g*PPOS + pp)*8;
      #pragma unroll
      for (int dy = 0; dy < 3; ++dy)
        #pragma unroll
        for (int dx = 0; dx < 3; ++dx)
          dst[dy*3+dx] = *(const half8*)(exg + ((long)(dy-1)*PW + (dx-1))*8);
    };
    // consume taps for group g
    auto COMP = [&](const half8* a, int g) {
      const _Float16* wp = wT + g*8;
      half8 w[9];
      #pragma unroll
      for (int tap = 0; tap < 9; ++tap)
        w[tap] = *(const half8*)(wp + tap*192);
      half8 bv8 = *(const half8*)(bB + g*8);
      half2v ac0 = {bv8[0], bv8[1]};
      half2v ac1 = {bv8[2], bv8[3]};
      half2v ac2 = {bv8[4], bv8[5]};
      half2v ac3 = {bv8[6], bv8[7]};
      #pragma unroll
      for (int tap = 0; tap < 9; ++tap) {
        ac0 += half2v{a[tap][0],a[tap][1]} * half2v{w[tap][0],w[tap][1]};
        ac1 += half2v{a[tap][2],a[tap][3]} * half2v{w[tap][2],w[tap][3]};
        ac2 += half2v{a[tap][4],a[tap][5]} * half2v{w[tap][4],w[tap][5]};
        ac3 += half2v{a[tap][6],a[tap][7]} * half2v{w[tap][6],w[tap][7]};
      }
      half8 o;
      half2v* oh = (half2v*)&o;
      oh[0] = pkrtz(silu_f((float)ac0[0]), silu_f((float)ac0[1]));
      oh[1] = pkrtz(silu_f((float)ac1[0]), silu_f((float)ac1[1]));
      oh[2] = pkrtz(silu_f((float)ac2[0]), silu_f((float)ac2[1]));
      oh[3] = pkrtz(silu_f((float)ac3[0]), silu_f((float)ac3[1]));
      *(half8*)(lds + lane*196 + g*8) = o;
    };

    LOADT(A0, wv);                       // pass 0 taps
    #pragma unroll
    for (int p = 0; p < 3; ++p) {
      const int g0 = (2*p)*4 + wv;
      const int g1 = (2*p+1)*4 + wv;
      LOADT(A1, g1);                     // prefetch pass 2p+1
      COMP(A0, g0);                      // compute pass 2p
      if (p < 2) LOADT(A0, (2*p+2)*4 + wv);   // prefetch pass 2p+2
      COMP(A1, g1);                      // compute pass 2p+1
    }
  }
  __syncthreads();

  // ---- phase 2: proj GEMM K=192 -> 96 (A = W2 co-major, B = dw acts) ----
  floatx4 pacc[6];
  {
    const _Float16* Ap = wbf + OFF_W2 + bz*55296 + lvl*18432 + ((long)mr)*192 + quad*8;
    floatx4 zero = {0.f,0.f,0.f,0.f};
    #pragma unroll
    for (int j=0;j<6;++j) pacc[j] = zero;

    #pragma unroll
    for (int k=0; k<6; ++k) {
      half8 af = *(const half8*)(lds + (wv*16 + mr)*196 + k*32 + quad*8);
      half8 wf[6];
      #pragma unroll
      for (int mt=0; mt<6; ++mt) wf[mt] = *(const half8*)(Ap + (long)mt*16*192);
      #pragma unroll
      for (int mt=0; mt<6; ++mt)
        pacc[mt] = __builtin_amdgcn_mfma_f32_16x16x32_f16(wf[mt], af, pacc[mt], 0, 0, 0);
      Ap += 32;
    }
  }
  __syncthreads();    // all dw-LDS reads done; safe to overwrite with ldsP

  // ---- epilogue: + bias + prefetched residual -> ldsP [pos][co] ----
  {
    const float* bp2 = b2 + lvl*96;
    int row = wv*16 + mr;
    #pragma unroll
    for (int mt=0; mt<6; ++mt) {
      int co = mt*16 + quad*4;
      float4 bv = *(const float4*)(bp2 + co);
      half4v o;
      o[0] = (_Float16)(pacc[mt][0] + bv.x + (float)rsv[mt][0]);
      o[1] = (_Float16)(pacc[mt][1] + bv.y + (float)rsv[mt][1]);
      o[2] = (_Float16)(pacc[mt][2] + bv.z + (float)rsv[mt][2]);
      o[3] = (_Float16)(pacc[mt][3] + bv.w + (float)rsv[mt][3]);
      *(half4v*)(ldsP + row*PSTRIDE + co) = o;
    }
  }
  // heads read only this wave's 16 rows -> no barrier.

  // ---- phase 3: heads ----
  if (bz == 0) {
    const _Float16* Bp = wbf + OFF_HEAD + lvl*7680 + ((long)mr)*96 + quad*8;
    const float* bp = hb + lvl*80;
    floatx4 zero = {0.f,0.f,0.f,0.f};
    floatx4 acc[5];
    #pragma unroll
    for (int j=0;j<5;++j) acc[j] = zero;

    #pragma unroll
    for (int k=0; k<3; ++k) {
      half8 a = *(const half8*)(ldsP + (wv*16 + mr)*PSTRIDE + k*32 + quad*8);
      half8 b[5];
      #pragma unroll
      for (int nt=0; nt<5; ++nt)
        b[nt] = *(const half8*)(Bp + (long)nt*16*96 + k*32);
      #pragma unroll
      for (int nt=0; nt<5; ++nt)
        acc[nt] = __builtin_amdgcn_mfma_f32_16x16x32_f16(a, b[nt], acc[nt], 0, 0, 0);
    }

    #pragma unroll
    for (int nt=0; nt<5; ++nt) {
      int co = nt*16 + mr;
      float bv = bp[co];
      int pos = m0 + wv*16 + quad*4;
      #pragma unroll
      for (int r=0; r<4; ++r) {
        uint32 mm = (uint32)(pos + r - noff);
        uint32 bb = (uint32)(((unsigned long long)mm * MB) >> 32);
        uint32 rpp = mm - bb*HW;
        out[((long)(bb*8400 + a0 + rpp))*85 + 5 + co] = sigm_f(acc[nt][r] + bv);
      }
    }
  } else {
    const _Float16* Bp = wbf + OFF_ROBJ + lvl*1536 + ((long)mr)*96 + quad*8;
    float bv = (mr < 4) ? rb[lvl*4 + mr] : ((mr == 4) ? ob[lvl] : 0.f);
    float sc = (lvl==0) ? 8.f : (lvl==1 ? 16.f : 32.f);
    floatx4 acc = {0.f,0.f,0.f,0.f};
    #pragma unroll
    for (int k=0; k<3; ++k) {
      half8 a = *(const half8*)(ldsP + (wv*16 + mr)*PSTRIDE + k*32 + quad*8);
      half8 b = *(const half8*)(Bp + k*32);
      acc = __builtin_amdgcn_mfma_f32_16x16x32_f16(a, b, acc, 0, 0, 0);
    }
    #pragma unroll
    for (int r=0; r<4; ++r) {
      int pos = m0 + wv*16 + quad*4 + r;
      uint32 mm = (uint32)(pos - noff);
      uint32 bb = (uint32)(((unsigned long long)mm * MB) >> 32);
      uint32 rpp = mm - bb*HW;
      uint32 yy = (rpp * MW) >> 22;
      uint32 xx = rpp - yy*W;
      float v = acc[r] + bv;
      float o;
      if      (mr == 0) o = (v + (float)xx)*sc;
      else if (mr == 1) o = (v + (float)yy)*sc;
      else if (mr <  4) o = __expf(v)*sc;
      else              o = sigm_f(v);
      if (mr < 5)
        out[((long)(bb*8400 + a0 + rpp))*85 + mr] = o;
    }
  }
}

extern "C" void kernel_launch(void* const* d_in, const int* in_sizes, int n_in,
                              void* d_out, int out_size, void* d_ws, size_t ws_size,
                              hipStream_t stream)
{
  bool dict = (in_sizes[1] == 96*128);
  const float* X[3]; const float* SW[3]; const float* SB[3];
  if (dict) {
    X[0]=(const float*)d_in[0]; SW[0]=(const float*)d_in[1]; SB[0]=(const float*)d_in[2];
    X[1]=(const float*)d_in[3]; SW[1]=(const float*)d_in[4]; SB[1]=(const float*)d_in[5];
    X[2]=(const float*)d_in[6]; SW[2]=(const float*)d_in[7]; SB[2]=(const float*)d_in[8];
  } else {
    X[0]=(const float*)d_in[0]; X[1]=(const float*)d_in[1]; X[2]=(const float*)d_in[2];
    SW[0]=(const float*)d_in[3]; SB[0]=(const float*)d_in[4];
    SW[1]=(const float*)d_in[5]; SB[1]=(const float*)d_in[6];
    SW[2]=(const float*)d_in[7]; SB[2]=(const float*)d_in[8];
  }
  const float* br_w1[2] = {(const float*)d_in[9],  (const float*)d_in[15]};
  const float* br_b1[2] = {(const float*)d_in[10], (const float*)d_in[16]};
  const float* br_wd[2] = {(const float*)d_in[11], (const float*)d_in[17]};
  const float* br_bd[2] = {(const float*)d_in[12], (const float*)d_in[18]};
  const float* br_w2[2] = {(const float*)d_in[13], (const float*)d_in[19]};
  const float* br_b2[2] = {(const float*)d_in[14], (const float*)d_in[20]};
  const float* clsp_w=(const float*)d_in[21]; const float* clsp_b=(const float*)d_in[22];
  const float* regp_w=(const float*)d_in[23]; const float* regp_b=(const float*)d_in[24];
  const float* objp_w=(const float*)d_in[25]; const float* objp_b=(const float*)d_in[26];

  float* out = (float*)d_out;

  _Float16* wbf   = (_Float16*)d_ws;
  _Float16* stemO = wbf + WTOT;
  _Float16* bufA  = stemO + 12902400;

  // 1. weights/bias -> fp16 blob
  wconv_k<<<1353,256,0,stream>>>(SW[0],SW[1],SW[2],br_w1[0],br_w1[1],
                                 br_w2[0],br_w2[1],clsp_w,br_wd[0],br_wd[1],
                                 regp_w,objp_w,br_bd[0],br_bd[1],wbf);

  // 2. zero the padded borders of the expand buffers
  zpad_k<<<1716,256,0,stream>>>(bufA);

  // 3. stem GEMM straight from NCHW fp32, channel-major output
  stem_k<<<1050,256,0,stream>>>(X[0],X[1],X[2],wbf,SB[0],SB[1],SB[2],stemO);

  // 4. expand GEMM, both branches, channel-major padded output
  expand2_k<<<dim3(1050,2,2),256,0,stream>>>(stemO, wbf, br_b1[0], br_b1[1], bufA);

  // 5. FUSED dw3x3 + project + residual + heads (pipelined phase 1)
  dwprojhead_k<<<dim3(2100,2),256,0,stream>>>(
      bufA, wbf, br_b2[0], br_b2[1], stemO,
      clsp_b, regp_b, objp_b, out);
}

// Round 11
// 231.117 us; speedup vs baseline: 1.0407x; 1.0384x over previous
//
#include <hip/hip_runtime.h>

typedef unsigned int uint32;
using half2v  = __attribute__((ext_vector_type(2))) _Float16;
using half4v  = __attribute__((ext_vector_type(4))) _Float16;
using half8   = __attribute__((ext_vector_type(8))) _Float16;
using floatx4 = __attribute__((ext_vector_type(4))) float;

__device__ __forceinline__ float sigm_f(float x){
  return __builtin_amdgcn_rcpf(1.0f + __expf(-x));
}
__device__ __forceinline__ float silu_f(float x){ return x * sigm_f(x); }

__device__ __forceinline__ half2v pkrtz(float a, float b){
  return __builtin_bit_cast(half2v, __builtin_amdgcn_cvt_pkrtz(a, b));
}

// async global->LDS, 16B per lane, zero VGPR cost. dst is wave-uniform base;
// HW writes lane i at dst + i*16B. src is per-lane.
__device__ __forceinline__ void gll16(const _Float16* src, _Float16* ldsDst){
  __builtin_amdgcn_global_load_lds(
      (const __attribute__((address_space(1))) uint32*)src,
      (__attribute__((address_space(3))) uint32*)ldsDst, 16, 0, 0);
}

// ---------------------------------------------------------------------------
// fp16 weight blob layout (element offsets): see previous rounds.
// ---------------------------------------------------------------------------
#define OFF_W2    196608
#define OFF_HEAD  307200
#define OFF_WDT   330240
#define OFF_ROBJ  340608
#define OFF_DWB   345216
#define WTOT      346368

// padded expand buffer, CHANNEL-GROUP-MAJOR: per branch [g=24][pp=143552][8ch]
#define PPOS 143552L
#define EXPAD_ELEMS 27561984L   // 24*143552*8
// stem output, CHANNEL-GROUP-MAJOR: [g=12][n=134400][8ch]
#define NDW  134400L

__global__ __launch_bounds__(256) void wconv_k(
    const float* __restrict__ s0, const float* __restrict__ s1,
    const float* __restrict__ s2, const float* __restrict__ cw1,
    const float* __restrict__ rw1, const float* __restrict__ cw2,
    const float* __restrict__ rw2, const float* __restrict__ chw,
    const float* __restrict__ cwd, const float* __restrict__ rwd,
    const float* __restrict__ rpw, const float* __restrict__ opw,
    const float* __restrict__ cbd, const float* __restrict__ rbd,
    _Float16* __restrict__ dst)
{
  int i = blockIdx.x*256 + threadIdx.x;
  if (i >= WTOT) return;
  float v;
  if (i < OFF_WDT) {
    const float* p; int off;
    if      (i < 12288)  { p = s0;  off = i; }
    else if (i < 36864)  { p = s1;  off = i - 12288; }
    else if (i < 86016)  { p = s2;  off = i - 36864; }
    else if (i < 141312) { p = cw1; off = i - 86016; }
    else if (i < 196608) { p = rw1; off = i - 141312; }
    else if (i < 251904) { p = cw2; off = i - 196608; }
    else if (i < 307200) { p = rw2; off = i - 251904; }
    else                 { p = chw; off = i - 307200; }
    v = p[off];
  } else if (i < OFF_ROBJ) {
    int rel = i - OFF_WDT;
    int br = rel / 5184; int r2 = rel - br*5184;
    int lvl = r2 / 1728; int r3 = r2 - lvl*1728;
    int j = r3 / 192;    int c = r3 - j*192;
    const float* wd = br ? rwd : cwd;
    v = wd[lvl*1728 + c*9 + j];
  } else if (i < OFF_DWB) {
    int rel = i - OFF_ROBJ;
    int lvl = rel / 1536; int r2 = rel - lvl*1536;
    int co = r2 / 96;     int k = r2 - co*96;
    v = (co < 4) ? rpw[lvl*384 + co*96 + k] : (co == 4 ? opw[lvl*96 + k] : 0.f);
  } else {
    int rel = i - OFF_DWB;
    int br = rel / 576;  int r2 = rel - br*576;
    int lvl = r2 / 192;  int c = r2 - lvl*192;
    v = (br ? rbd : cbd)[lvl*192 + c];
  }
  dst[i] = (_Float16)v;
}

// ---------------------------------------------------------------------------
// Zero the 1-pixel border of the padded expand buffers (channel-major).
// ---------------------------------------------------------------------------
__global__ __launch_bounds__(256) void zpad_k(_Float16* __restrict__ exBase)
{
  int ci = blockIdx.x*256 + threadIdx.x;
  if (ci >= 439296) return;
  int br = ci / 219648; int r = ci - br*219648;
  int W, PLB, rem, perimg;
  if (r < 124416)      { W=80; PLB=0;      rem = r;          perimg = 7776; }
  else if (r < 187392) { W=40; PLB=107584; rem = r - 124416; perimg = 3936; }
  else                 { W=20; PLB=135808; rem = r - 187392; perimg = 2016; }
  int b = rem / perimg; int t3 = rem - b*perimg;
  int p = t3 / 24; int g = t3 - p*24;
  int PW = W + 2;
  int row, col;
  if (p < 2*PW) { row = (p >= PW) ? (W+1) : 0; col = (p >= PW) ? (p - PW) : p; }
  else { int q = p - 2*PW; row = 1 + (q >> 1); col = (q & 1) ? (W+1) : 0; }
  long pp = (long)PLB + (long)b*PW*PW + row*PW + col;
  half8 z = {(_Float16)0,(_Float16)0,(_Float16)0,(_Float16)0,
             (_Float16)0,(_Float16)0,(_Float16)0,(_Float16)0};
  *(half8*)(exBase + br*EXPAD_ELEMS + ((long)g*PPOS + pp)*8) = z;
}

// ---------------------------------------------------------------------------
// Stem GEMM from NCHW fp32, fp16 MFMA. Output CHANNEL-GROUP-MAJOR [g][n][8].
// ---------------------------------------------------------------------------
__global__ __launch_bounds__(256) void stem_k(
    const float* __restrict__ x0, const float* __restrict__ x1,
    const float* __restrict__ x2, const _Float16* __restrict__ Wb,
    const float* __restrict__ sb0, const float* __restrict__ sb1,
    const float* __restrict__ sb2, _Float16* __restrict__ Out)
{
  const int m0 = blockIdx.x << 7;
  const int lvl = (m0 < 102400) ? 0 : (m0 < 128000 ? 1 : 2);
  const int CIN = (lvl==0)?128:(lvl==1?256:512);
  const int HW  = (lvl==0)?6400:(lvl==1?1600:400);
  const int noff= (lvl==0)?0:(lvl==1?102400:128000);
  const float* X = (lvl==0)?x0:(lvl==1?x1:x2);
  const _Float16* Wl = Wb + ((lvl==0)?0:(lvl==1?12288:36864));
  const float* bias = (lvl==0)?sb0:(lvl==1?sb1:sb2);

  int t=threadIdx.x, lane=t&63, wv=t>>6, mr=lane&15, quad=lane>>4;

  int idx[2];
  #pragma unroll
  for (int nt=0; nt<2; ++nt) {
    int n = m0 + wv*32 + nt*16 + mr;
    int m = n - noff; int b_ = m / HW; int p = m - b_*HW;
    idx[nt] = (b_*CIN + quad*8)*HW + p;
  }
  const _Float16* Ap = Wl + mr*CIN + quad*8;

  floatx4 zero = {0.f,0.f,0.f,0.f};
  floatx4 acc[6][2];
  #pragma unroll
  for (int i=0;i<6;++i)
    #pragma unroll
    for (int j=0;j<2;++j) acc[i][j] = zero;

  for (int k=0; k<CIN; k+=32) {
    half8 a[6], b[2];
    #pragma unroll
    for (int mt=0; mt<6; ++mt) a[mt] = *(const half8*)(Ap + mt*16*CIN);
    #pragma unroll
    for (int nt=0; nt<2; ++nt) {
      float f[8];
      #pragma unroll
      for (int j=0;j<8;++j) f[j] = X[idx[nt] + j*HW];
      half2v* bh = (half2v*)&b[nt];
      #pragma unroll
      for (int j=0;j<4;++j) bh[j] = pkrtz(f[2*j], f[2*j+1]);
    }
    #pragma unroll
    for (int mt=0; mt<6; ++mt)
      #pragma unroll
      for (int nt=0; nt<2; ++nt)
        acc[mt][nt] = __builtin_amdgcn_mfma_f32_16x16x32_f16(a[mt], b[nt], acc[mt][nt], 0, 0, 0);
    Ap += 32;
    #pragma unroll
    for (int nt=0; nt<2; ++nt) idx[nt] += 32*HW;
  }

  #pragma unroll
  for (int mt=0; mt<6; ++mt) {
    float4 bv = *(const float4*)(bias + mt*16 + quad*4);
    int co = mt*16 + quad*4;
    int g = co >> 3; int h = co & 7;
    #pragma unroll
    for (int nt=0; nt<2; ++nt) {
      int pos = m0 + wv*32 + nt*16 + mr;
      half4v o;
      o[0] = (_Float16)silu_f(acc[mt][nt][0] + bv.x);
      o[1] = (_Float16)silu_f(acc[mt][nt][1] + bv.y);
      o[2] = (_Float16)silu_f(acc[mt][nt][2] + bv.z);
      o[3] = (_Float16)silu_f(acc[mt][nt][3] + bv.w);
      *(half4v*)(Out + ((long)g*NDW + pos)*8 + h) = o;
    }
  }
}

// ---------------------------------------------------------------------------
// Expand GEMM, both branches: channel-major stemO -> channel-major padded.
// grid (1050, 2, 2). XCD-bijective swizzle on blockIdx.x.
// ---------------------------------------------------------------------------
__global__ __launch_bounds__(256) void expand2_k(
    const _Float16* __restrict__ A, const _Float16* __restrict__ wbf,
    const float* __restrict__ b1c, const float* __restrict__ b1r,
    _Float16* __restrict__ OutBase)
{
  const int bz = blockIdx.z;
  const _Float16* Wb = wbf + 86016 + bz*55296;
  _Float16* Out = OutBase + bz*EXPAD_ELEMS;
  const float* b1 = bz ? b1r : b1c;

  int orig = blockIdx.x;
  int xcd = orig & 7; int loc = orig >> 3;
  int bx = (xcd < 2 ? xcd*132 : 2*132 + (xcd-2)*131) + loc;

  const int m0 = bx << 7;
  const int lvl = (m0 < 102400) ? 0 : (m0 < 128000 ? 1 : 2);
  const int HW  = (lvl==0)?6400:(lvl==1?1600:400);
  const int W   = (lvl==0)?80:(lvl==1?40:20);
  const int noff= (lvl==0)?0:(lvl==1?102400:128000);
  const int PLB = (lvl==0)?0:(lvl==1?107584:135808);
  const int PW  = W + 2;
  const int co0 = blockIdx.y * 96;
  int t = threadIdx.x, lane = t & 63, wv = t >> 6;
  int mr = lane & 15, quad = lane >> 4;
  const _Float16* Ap0 = A + ((long)quad*NDW + (m0 + wv*32 + mr))*8;  // acts, ch-major
  const _Float16* Bp = Wb + ((long)(co0 + mr))*96 + quad*8;          // weights
  const float* bp = b1 + lvl*192 + co0;

  floatx4 zero = {0.f,0.f,0.f,0.f};
  floatx4 acc[6][2];     // [co tile][pos tile]
  #pragma unroll
  for (int i=0;i<6;++i)
    #pragma unroll
    for (int j=0;j<2;++j) acc[i][j] = zero;

  #pragma unroll
  for (int k=0; k<3; ++k) {
    half8 wf[6], af[2];
    #pragma unroll
    for (int mt=0; mt<6; ++mt) wf[mt] = *(const half8*)(Bp + (long)mt*16*96);
    #pragma unroll
    for (int nt=0; nt<2; ++nt)
      af[nt] = *(const half8*)(Ap0 + ((long)k*4*NDW)*8 + nt*16*8);
    #pragma unroll
    for (int mt=0; mt<6; ++mt)
      #pragma unroll
      for (int nt=0; nt<2; ++nt)
        acc[mt][nt] = __builtin_amdgcn_mfma_f32_16x16x32_f16(wf[mt], af[nt], acc[mt][nt], 0, 0, 0);
    Bp += 32;
  }

  long pp2[2];
  #pragma unroll
  for (int nt=0; nt<2; ++nt) {
    int gm = m0 + wv*32 + nt*16 + mr;
    int m = gm - noff; int b_ = m / HW; int rp = m - b_*HW;
    int y = rp / W;  int x = rp - y*W;
    pp2[nt] = PLB + ((long)b_*PW + (y+1))*PW + (x+1);
  }

  #pragma unroll
  for (int mt=0; mt<6; ++mt) {
    float4 bv = *(const float4*)(bp + mt*16 + quad*4);
    int co = co0 + mt*16 + quad*4;
    int g = co >> 3;            // channel group
    int h = (co & 4);           // 0 or 4 within group
    #pragma unroll
    for (int nt=0; nt<2; ++nt) {
      half4v o;
      o[0] = (_Float16)silu_f(acc[mt][nt][0] + bv.x);
      o[1] = (_Float16)silu_f(acc[mt][nt][1] + bv.y);
      o[2] = (_Float16)silu_f(acc[mt][nt][2] + bv.z);
      o[3] = (_Float16)silu_f(acc[mt][nt][3] + bv.w);
      *(half4v*)(Out + ((long)g*PPOS + pp2[nt])*8 + h) = o;
    }
  }
}

// ---------------------------------------------------------------------------
// FUSED dw3x3 + proj + heads.
//  lvl0/lvl1: block = 8x8 spatial tile. ALL 24 group-halos (10x10x8ch)
//  staged into LDS via 48 async global_load_lds (zero VGPR cost, one
//  latency round, one barrier). dw computed in-register per (pos, 4k+quad)
//  = proj MFMA B-fragment directly (round-9 trick), taps from LDS.
//  lvl2 (5% of blocks): round-9 linear direct-global path.
// LDS: halo 38400B + ldsP 13312B = 51712B -> 3 blocks/CU.
// grid (2100, 2): x in [0,1600) lvl0 tiles, [1600,2000) lvl1, [2000,2100) lvl2.
// ---------------------------------------------------------------------------
#define PSTRIDE 104
__global__ __launch_bounds__(256, 3) void dwprojhead_k(
    const _Float16* __restrict__ exBase, const _Float16* __restrict__ wbf,
    const float* __restrict__ b2_c, const float* __restrict__ b2_r,
    const _Float16* __restrict__ resid,
    const float* __restrict__ hb, const float* __restrict__ rb,
    const float* __restrict__ ob, float* __restrict__ out)
{
  __shared__ _Float16 halo[24*800];      // [g][100 entries][8ch]
  __shared__ _Float16 ldsP[64*PSTRIDE];  // proj out [pos][96], intra-wave only
  const int bz = blockIdx.y;
  const _Float16* ex = exBase + bz*EXPAD_ELEMS;
  const float* b2 = bz ? b2_r : b2_c;

  int orig = blockIdx.x;
  int xcd = orig & 7; int loc = orig >> 3;
  int bx = (xcd < 4 ? xcd*263 : 4*263 + (xcd-4)*262) + loc;

  int lvl, W, HW, noff, a0, PLB;
  int b_ = 0, y0 = 0, x0 = 0, m0 = 0;
  bool tilep;
  if (bx < 1600) {
    tilep = true; lvl = 0; W = 80; HW = 6400; noff = 0;      a0 = 0;    PLB = 0;
    b_ = bx / 100; int tl = bx - b_*100;
    y0 = (tl / 10) * 8; x0 = (tl - (tl/10)*10) * 8;
  } else if (bx < 2000) {
    tilep = true; lvl = 1; W = 40; HW = 1600; noff = 102400; a0 = 6400; PLB = 107584;
    int rel = bx - 1600; b_ = rel / 25; int tl = rel - b_*25;
    y0 = (tl / 5) * 8; x0 = (tl - (tl/5)*5) * 8;
  } else {
    tilep = false; lvl = 2; W = 20; HW = 400; noff = 128000; a0 = 8000; PLB = 135808;
    m0 = 128000 + ((bx - 2000) << 6);
  }
  const int PW = W + 2;

  int t = threadIdx.x, lane = t & 63, wv = t >> 6;
  int mr = lane & 15, quad = lane >> 4;
  const int p = wv*16 + mr;              // this thread's tile-local position

  const _Float16* wT = wbf + OFF_WDT + bz*5184 + lvl*1728;
  const _Float16* bB = wbf + OFF_DWB + bz*576 + lvl*192;
  const _Float16* Ap = wbf + OFF_W2 + bz*55296 + lvl*18432 + ((long)mr)*192 + quad*8;

  // this thread's global position n
  int n;
  if (tilep) n = noff + b_*HW + (y0 + (p>>3))*W + x0 + (p&7);
  else       n = m0 + p;

  floatx4 pacc[6];
  {
    floatx4 zero = {0.f,0.f,0.f,0.f};
    #pragma unroll
    for (int j=0;j<6;++j) pacc[j] = zero;
  }

  half4v rsv[6];   // resid prefetch

  if (tilep) {
    // ---- stage all 24 group halos via async global_load_lds ----
    const long pb00 = (long)PLB + ((long)b_*PW + y0)*PW + x0;  // padded (y0-1,x0-1)
    {
      int e1 = lane;
      int hy1 = e1 / 10, hx1 = e1 - hy1*10;
      long s1 = pb00 + hy1*PW + hx1;
      int e2 = 64 + lane;
      int hy2 = e2 / 10, hx2 = e2 - hy2*10;
      long s2 = pb00 + hy2*PW + hx2;
      #pragma unroll
      for (int j = 0; j < 6; ++j) {
        int g = wv*6 + j;
        gll16(ex + ((long)g*PPOS + s1)*8, halo + g*800);
        if (lane < 36)
          gll16(ex + ((long)g*PPOS + s2)*8, halo + g*800 + 512);
      }
    }
    // resid prefetch (independent of staging)
    #pragma unroll
    for (int mt=0; mt<6; ++mt) {
      int co = mt*16 + quad*4;
      int g = co >> 3; int h = co & 7;
      rsv[mt] = *(const half4v*)(resid + ((long)g*NDW + n)*8 + h);
    }
    __syncthreads();   // drain global_load_lds + make halo visible

    // ---- fused dw + proj k-loop, taps from LDS ----
    const int ty = p >> 3, tx = p & 7;
    const _Float16* hb0 = halo + (ty*10 + tx)*8;   // entry (ty,tx) base
    for (int k = 0; k < 6; ++k) {
      const int g = 4*k + quad;
      const _Float16* hg = hb0 + g*800;
      const _Float16* wp = wT + g*8;

      half8 a[9], w[9];
      #pragma unroll
      for (int dy = 0; dy < 3; ++dy)
        #pragma unroll
        for (int dx = 0; dx < 3; ++dx)
          a[dy*3+dx] = *(const half8*)(hg + (dy*10 + dx)*8);
      #pragma unroll
      for (int tap = 0; tap < 9; ++tap)
        w[tap] = *(const half8*)(wp + tap*192);
      half8 bv8 = *(const half8*)(bB + g*8);
      half8 wf[6];
      #pragma unroll
      for (int mt = 0; mt < 6; ++mt)
        wf[mt] = *(const half8*)(Ap + (long)mt*16*192 + k*32);

      half2v ac0 = {bv8[0], bv8[1]};
      half2v ac1 = {bv8[2], bv8[3]};
      half2v ac2 = {bv8[4], bv8[5]};
      half2v ac3 = {bv8[6], bv8[7]};
      #pragma unroll
      for (int tap = 0; tap < 9; ++tap) {
        ac0 += half2v{a[tap][0],a[tap][1]} * half2v{w[tap][0],w[tap][1]};
        ac1 += half2v{a[tap][2],a[tap][3]} * half2v{w[tap][2],w[tap][3]};
        ac2 += half2v{a[tap][4],a[tap][5]} * half2v{w[tap][4],w[tap][5]};
        ac3 += half2v{a[tap][6],a[tap][7]} * half2v{w[tap][6],w[tap][7]};
      }
      half8 af;
      {
        half2v* oh = (half2v*)&af;
        oh[0] = pkrtz(silu_f((float)ac0[0]), silu_f((float)ac0[1]));
        oh[1] = pkrtz(silu_f((float)ac1[0]), silu_f((float)ac1[1]));
        oh[2] = pkrtz(silu_f((float)ac2[0]), silu_f((float)ac2[1]));
        oh[3] = pkrtz(silu_f((float)ac3[0]), silu_f((float)ac3[1]));
      }
      #pragma unroll
      for (int mt = 0; mt < 6; ++mt)
        pacc[mt] = __builtin_amdgcn_mfma_f32_16x16x32_f16(wf[mt], af, pacc[mt], 0, 0, 0);
    }
  } else {
    // ---- lvl2 linear path: direct-global taps, in-register (round 9) ----
    uint32 mm = (uint32)(n - noff);
    uint32 bb = (uint32)(((unsigned long long)mm * 10737419u) >> 32);   // /400
    uint32 rp = mm - bb*400;
    uint32 yy = (rp * 209716u) >> 22;                                   // /20
    uint32 xx = rp - yy*20;
    long pp = (long)PLB + ((long)bb*PW + (yy+1))*PW + (xx+1);

    #pragma unroll
    for (int mt=0; mt<6; ++mt) {
      int co = mt*16 + quad*4;
      int g = co >> 3; int h = co & 7;
      rsv[mt] = *(const half4v*)(resid + ((long)g*NDW + n)*8 + h);
    }

    for (int k = 0; k < 6; ++k) {
      const int g = 4*k + quad;
      const _Float16* exg = ex + ((long)g*PPOS + pp)*8;
      const _Float16* wp = wT + g*8;

      half8 a[9], w[9];
      #pragma unroll
      for (int dy = 0; dy < 3; ++dy)
        #pragma unroll
        for (int dx = 0; dx < 3; ++dx)
          a[dy*3+dx] = *(const half8*)(exg + ((long)(dy-1)*PW + (dx-1))*8);
      #pragma unroll
      for (int tap = 0; tap < 9; ++tap)
        w[tap] = *(const half8*)(wp + tap*192);
      half8 bv8 = *(const half8*)(bB + g*8);
      half8 wf[6];
      #pragma unroll
      for (int mt = 0; mt < 6; ++mt)
        wf[mt] = *(const half8*)(Ap + (long)mt*16*192 + k*32);

      half2v ac0 = {bv8[0], bv8[1]};
      half2v ac1 = {bv8[2], bv8[3]};
      half2v ac2 = {bv8[4], bv8[5]};
      half2v ac3 = {bv8[6], bv8[7]};
      #pragma unroll
      for (int tap = 0; tap < 9; ++tap) {
        ac0 += half2v{a[tap][0],a[tap][1]} * half2v{w[tap][0],w[tap][1]};
        ac1 += half2v{a[tap][2],a[tap][3]} * half2v{w[tap][2],w[tap][3]};
        ac2 += half2v{a[tap][4],a[tap][5]} * half2v{w[tap][4],w[tap][5]};
        ac3 += half2v{a[tap][6],a[tap][7]} * half2v{w[tap][6],w[tap][7]};
      }
      half8 af;
      {
        half2v* oh = (half2v*)&af;
        oh[0] = pkrtz(silu_f((float)ac0[0]), silu_f((float)ac0[1]));
        oh[1] = pkrtz(silu_f((float)ac1[0]), silu_f((float)ac1[1]));
        oh[2] = pkrtz(silu_f((float)ac2[0]), silu_f((float)ac2[1]));
        oh[3] = pkrtz(silu_f((float)ac3[0]), silu_f((float)ac3[1]));
      }
      #pragma unroll
      for (int mt = 0; mt < 6; ++mt)
        pacc[mt] = __builtin_amdgcn_mfma_f32_16x16x32_f16(wf[mt], af, pacc[mt], 0, 0, 0);
    }
  }

  // ---- epilogue: + bias + prefetched residual -> ldsP [pos][co] ----
  {
    const float* bp2 = b2 + lvl*96;
    #pragma unroll
    for (int mt=0; mt<6; ++mt) {
      int co = mt*16 + quad*4;
      float4 bv = *(const float4*)(bp2 + co);
      half4v o;
      o[0] = (_Float16)(pacc[mt][0] + bv.x + (float)rsv[mt][0]);
      o[1] = (_Float16)(pacc[mt][1] + bv.y + (float)rsv[mt][1]);
      o[2] = (_Float16)(pacc[mt][2] + bv.z + (float)rsv[mt][2]);
      o[3] = (_Float16)(pacc[mt][3] + bv.w + (float)rsv[mt][3]);
      *(half4v*)(ldsP + p*PSTRIDE + co) = o;
    }
  }
  // heads read only this wave's 16 rows -> no barrier (same-wave ds ordering).

  // ---- heads ----
  if (bz == 0) {
    const _Float16* Bp = wbf + OFF_HEAD + lvl*7680 + ((long)mr)*96 + quad*8;
    const float* bp = hb + lvl*80;
    floatx4 zero = {0.f,0.f,0.f,0.f};
    floatx4 acc[5];
    #pragma unroll
    for (int j=0;j<5;++j) acc[j] = zero;

    #pragma unroll
    for (int k=0; k<3; ++k) {
      half8 a = *(const half8*)(ldsP + (wv*16 + mr)*PSTRIDE + k*32 + quad*8);
      half8 b[5];
      #pragma unroll
      for (int nt=0; nt<5; ++nt)
        b[nt] = *(const half8*)(Bp + (long)nt*16*96 + k*32);
      #pragma unroll
      for (int nt=0; nt<5; ++nt)
        acc[nt] = __builtin_amdgcn_mfma_f32_16x16x32_f16(a, b[nt], acc[nt], 0, 0, 0);
    }

    #pragma unroll
    for (int nt=0; nt<5; ++nt) {
      int co = nt*16 + mr;
      float bv = bp[co];
      #pragma unroll
      for (int r=0; r<4; ++r) {
        int pq = wv*16 + quad*4 + r;       // tile-local position
        int rpp, bb;
        if (tilep) { bb = b_; rpp = (y0 + (pq>>3))*W + x0 + (pq&7); }
        else {
          uint32 mm = (uint32)(m0 + pq - noff);
          bb = (int)(((unsigned long long)mm * 10737419u) >> 32);
          rpp = (int)(mm - (uint32)bb*400u);
        }
        out[((long)(bb*8400 + a0 + rpp))*85 + 5 + co] = sigm_f(acc[nt][r] + bv);
      }
    }
  } else {
    const _Float16* Bp = wbf + OFF_ROBJ + lvl*1536 + ((long)mr)*96 + quad*8;
    float bv = (mr < 4) ? rb[lvl*4 + mr] : ((mr == 4) ? ob[lvl] : 0.f);
    float sc = (lvl==0) ? 8.f : (lvl==1 ? 16.f : 32.f);
    floatx4 acc = {0.f,0.f,0.f,0.f};
    #pragma unroll
    for (int k=0; k<3; ++k) {
      half8 a = *(const half8*)(ldsP + (wv*16 + mr)*PSTRIDE + k*32 + quad*8);
      half8 b = *(const half8*)(Bp + k*32);
      acc = __builtin_amdgcn_mfma_f32_16x16x32_f16(a, b, acc, 0, 0, 0);
    }
    #pragma unroll
    for (int r=0; r<4; ++r) {
      int pq = wv*16 + quad*4 + r;
      int bb, rpp, yy, xx;
      if (tilep) {
        bb = b_; yy = y0 + (pq>>3); xx = x0 + (pq&7); rpp = yy*W + xx;
      } else {
        uint32 mm = (uint32)(m0 + pq - noff);
        bb = (int)(((unsigned long long)mm * 10737419u) >> 32);
        rpp = (int)(mm - (uint32)bb*400u);
        yy = (int)(((uint32)rpp * 209716u) >> 22);
        xx = rpp - yy*20;
      }
      float v = acc[r] + bv;
      float o;
      if      (mr == 0) o = (v + (float)xx)*sc;
      else if (mr == 1) o = (v + (float)yy)*sc;
      else if (mr <  4) o = __expf(v)*sc;
      else              o = sigm_f(v);
      if (mr < 5)
        out[((long)(bb*8400 + a0 + rpp))*85 + mr] = o;
    }
  }
}

extern "C" void kernel_launch(void* const* d_in, const int* in_sizes, int n_in,
                              void* d_out, int out_size, void* d_ws, size_t ws_size,
                              hipStream_t stream)
{
  bool dict = (in_sizes[1] == 96*128);
  const float* X[3]; const float* SW[3]; const float* SB[3];
  if (dict) {
    X[0]=(const float*)d_in[0]; SW[0]=(const float*)d_in[1]; SB[0]=(const float*)d_in[2];
    X[1]=(const float*)d_in[3]; SW[1]=(const float*)d_in[4]; SB[1]=(const float*)d_in[5];
    X[2]=(const float*)d_in[6]; SW[2]=(const float*)d_in[7]; SB[2]=(const float*)d_in[8];
  } else {
    X[0]=(const float*)d_in[0]; X[1]=(const float*)d_in[1]; X[2]=(const float*)d_in[2];
    SW[0]=(const float*)d_in[3]; SB[0]=(const float*)d_in[4];
    SW[1]=(const float*)d_in[5]; SB[1]=(const float*)d_in[6];
    SW[2]=(const float*)d_in[7]; SB[2]=(const float*)d_in[8];
  }
  const float* br_w1[2] = {(const float*)d_in[9],  (const float*)d_in[15]};
  const float* br_b1[2] = {(const float*)d_in[10], (const float*)d_in[16]};
  const float* br_wd[2] = {(const float*)d_in[11], (const float*)d_in[17]};
  const float* br_bd[2] = {(const float*)d_in[12], (const float*)d_in[18]};
  const float* br_w2[2] = {(const float*)d_in[13], (const float*)d_in[19]};
  const float* br_b2[2] = {(const float*)d_in[14], (const float*)d_in[20]};
  const float* clsp_w=(const float*)d_in[21]; const float* clsp_b=(const float*)d_in[22];
  const float* regp_w=(const float*)d_in[23]; const float* regp_b=(const float*)d_in[24];
  const float* objp_w=(const float*)d_in[25]; const float* objp_b=(const float*)d_in[26];

  float* out = (float*)d_out;

  _Float16* wbf   = (_Float16*)d_ws;
  _Float16* stemO = wbf + WTOT;
  _Float16* bufA  = stemO + 12902400;

  // 1. weights/bias -> fp16 blob
  wconv_k<<<1353,256,0,stream>>>(SW[0],SW[1],SW[2],br_w1[0],br_w1[1],
                                 br_w2[0],br_w2[1],clsp_w,br_wd[0],br_wd[1],
                                 regp_w,objp_w,br_bd[0],br_bd[1],wbf);

  // 2. zero the padded borders of the expand buffers
  zpad_k<<<1716,256,0,stream>>>(bufA);

  // 3. stem GEMM straight from NCHW fp32, channel-major output
  stem_k<<<1050,256,0,stream>>>(X[0],X[1],X[2],wbf,SB[0],SB[1],SB[2],stemO);

  // 4. expand GEMM, both branches, channel-major padded output
  expand2_k<<<dim3(1050,2,2),256,0,stream>>>(stemO, wbf, br_b1[0], br_b1[1], bufA);

  // 5. FUSED dw3x3 + project + residual + heads (async halo staging)
  dwprojhead_k<<<dim3(2100,2),256,0,stream>>>(
      bufA, wbf, br_b2[0], br_b2[1], stemO,
      clsp_b, regp_b, objp_b, out);
}